// Round 1
// baseline (1638.763 us; speedup 1.0000x reference)
//
#include <hip/hip_runtime.h>

#define Bdim 2
#define Tdim 2048
#define Edim 4096
#define Hdim 32
#define Ddim 128
#define Mdim (Bdim*Tdim)   // 4096
#define Kdim 4096

typedef int v4i __attribute__((ext_vector_type(4)));
typedef long long ll_t;

// ---------------- pack int32 -> int8 ----------------
__global__ __launch_bounds__(256) void pack_i8_kernel(const int* __restrict__ src,
                                                      char* __restrict__ dst, int n4) {
  int stride = gridDim.x * blockDim.x;
  for (int i = blockIdx.x * blockDim.x + threadIdx.x; i < n4; i += stride) {
    int4 x = ((const int4*)src)[i];
    char4 y;
    y.x = (char)x.x; y.y = (char)x.y; y.z = (char)x.z; y.w = (char)x.w;
    ((char4*)dst)[i] = y;
  }
}

// ---------------- int8 NT GEMM: C[m][n] = sum_k A[m][k]*B[n][k] ----------------
// OUT_MODE 0: int8 out = clamp(rint(acc*alpha + bias_i[n]))
// OUT_MODE 1: f32  out = acc*alpha + bias_f[n]
template<int OUT_MODE>
__global__ __launch_bounds__(256) void gemm_nt_i8(
    const char* __restrict__ A, const char* __restrict__ Bw,
    const int* __restrict__ bias_i, const float* __restrict__ bias_f,
    const float* __restrict__ alpha_p,
    char* __restrict__ out8, float* __restrict__ outf)
{
  const float alpha = alpha_p[0];
  const int tid = threadIdx.x;
  const int wave = tid >> 6, lane = tid & 63;
  const int quad = lane >> 4, l16 = lane & 15;
  const int wr = wave & 1, wc = wave >> 1;
  const int m0 = blockIdx.x * 128, n0 = blockIdx.y * 128;

  __shared__ __align__(16) char As[128 * 72];
  __shared__ __align__(16) char Bs[128 * 72];

  v4i acc[4][4];
#pragma unroll
  for (int i = 0; i < 4; i++)
#pragma unroll
    for (int c = 0; c < 4; c++) acc[i][c] = (v4i){0, 0, 0, 0};

  for (int k0 = 0; k0 < Kdim; k0 += 64) {
    __syncthreads();
#pragma unroll
    for (int it = 0; it < 2; ++it) {
      int c = tid + it * 256;            // 512 chunks of 16B per tile
      int row = c >> 2, koff = (c & 3) * 16;
      int4 avv = *(const int4*)(A + (size_t)(m0 + row) * Kdim + k0 + koff);
      int4 bvv = *(const int4*)(Bw + (size_t)(n0 + row) * Kdim + k0 + koff);
      *(ll_t*)(As + row * 72 + koff)     = ((const ll_t*)&avv)[0];
      *(ll_t*)(As + row * 72 + koff + 8) = ((const ll_t*)&avv)[1];
      *(ll_t*)(Bs + row * 72 + koff)     = ((const ll_t*)&bvv)[0];
      *(ll_t*)(Bs + row * 72 + koff + 8) = ((const ll_t*)&bvv)[1];
    }
    __syncthreads();
#pragma unroll
    for (int kk = 0; kk < 2; ++kk) {
      ll_t af[4], bf[4];
#pragma unroll
      for (int i = 0; i < 4; i++)
        af[i] = *(const ll_t*)(As + (64 * wr + 16 * i + l16) * 72 + kk * 32 + quad * 8);
#pragma unroll
      for (int c = 0; c < 4; c++)
        bf[c] = *(const ll_t*)(Bs + (64 * wc + 16 * c + l16) * 72 + kk * 32 + quad * 8);
#pragma unroll
      for (int i = 0; i < 4; i++)
#pragma unroll
        for (int c = 0; c < 4; c++)
          acc[i][c] = __builtin_amdgcn_mfma_i32_16x16x32_i8(af[i], bf[c], acc[i][c], 0, 0, 0);
    }
  }

#pragma unroll
  for (int i = 0; i < 4; i++) {
#pragma unroll
    for (int c = 0; c < 4; c++) {
      int gcol = n0 + 64 * wc + 16 * c + l16;
#pragma unroll
      for (int r = 0; r < 4; r++) {
        int grow = m0 + 64 * wr + 16 * i + quad * 4 + r;
        float y = (float)acc[i][c][r] * alpha;
        if (OUT_MODE == 0) {
          y += (float)bias_i[gcol];
          int q = (int)rintf(y);
          q = q < -128 ? -128 : (q > 127 ? 127 : q);
          out8[(size_t)grow * 4096 + gcol] = (char)q;
        } else {
          outf[(size_t)grow * 4096 + gcol] = y + bias_f[gcol];
        }
      }
    }
  }
}

// ---------------- fused int8 attention ----------------
// grid: (T/64, B*H). block: 256 threads (4 waves); wave w owns rows [t0+16w, t0+16w+16)
__global__ __launch_bounds__(256) void attn_kernel(
    const char* __restrict__ Q, const char* __restrict__ Kc, const char* __restrict__ Vc,
    const float* __restrict__ aqk_p, const float* __restrict__ apv_p,
    char* __restrict__ CTX)
{
  const int tid = threadIdx.x;
  const int wave = tid >> 6, lane = tid & 63;
  const int quad = lane >> 4, l16 = lane & 15;
  const int bh = blockIdx.y;
  const int b = bh >> 5, h = bh & (Hdim - 1);
  const int t0 = blockIdx.x * 64;
  const float a_qk = aqk_p[0], a_pv = apv_p[0];

  __shared__ __align__(16) char qs[64 * 144];
  __shared__ __align__(16) char ks[64 * 144];
  __shared__ __align__(16) char vts[128 * 80];
  __shared__ __align__(16) char ps[4][16 * 72];

  // stage Q tile once: 64 rows x 128 B
#pragma unroll
  for (int it = 0; it < 2; ++it) {
    int c = tid + it * 256;
    int row = c >> 3, koff = (c & 7) * 16;
    int4 v = *(const int4*)(Q + (size_t)(b * Tdim + t0 + row) * Edim + h * Ddim + koff);
    *(ll_t*)(qs + row * 144 + koff)     = ((const ll_t*)&v)[0];
    *(ll_t*)(qs + row * 144 + koff + 8) = ((const ll_t*)&v)[1];
  }

  float m_run[4], l_run[4];
#pragma unroll
  for (int r = 0; r < 4; r++) { m_run[r] = -__builtin_inff(); l_run[r] = 0.f; }

  const int ntiles = blockIdx.x + 1;

  // ---------- pass 1: exact row max & denom ----------
  for (int it = 0; it < ntiles; ++it) {
    int s0 = it * 64;
    __syncthreads();
#pragma unroll
    for (int i2 = 0; i2 < 2; ++i2) {
      int c = tid + i2 * 256;
      int row = c >> 3, koff = (c & 7) * 16;
      int4 v = *(const int4*)(Kc + (size_t)(b * Tdim + s0 + row) * Edim + h * Ddim + koff);
      *(ll_t*)(ks + row * 144 + koff)     = ((const ll_t*)&v)[0];
      *(ll_t*)(ks + row * 144 + koff + 8) = ((const ll_t*)&v)[1];
    }
    __syncthreads();

    float val[4][4];
#pragma unroll
    for (int c = 0; c < 4; c++) {
      v4i acc = (v4i){0, 0, 0, 0};
#pragma unroll
      for (int kk = 0; kk < 4; kk++) {
        ll_t a  = *(const ll_t*)(qs + (16 * wave + l16) * 144 + kk * 32 + quad * 8);
        ll_t bb = *(const ll_t*)(ks + (16 * c + l16) * 144 + kk * 32 + quad * 8);
        acc = __builtin_amdgcn_mfma_i32_16x16x32_i8(a, bb, acc, 0, 0, 0);
      }
      int s = s0 + 16 * c + l16;
#pragma unroll
      for (int r = 0; r < 4; r++) {
        int t = t0 + 16 * wave + quad * 4 + r;
        val[c][r] = (s <= t) ? (float)acc[r] * a_qk : -__builtin_inff();
      }
    }
#pragma unroll
    for (int r = 0; r < 4; r++) {
      float mt = fmaxf(fmaxf(val[0][r], val[1][r]), fmaxf(val[2][r], val[3][r]));
#pragma unroll
      for (int off = 1; off < 16; off <<= 1) mt = fmaxf(mt, __shfl_xor(mt, off, 16));
      float mn = fmaxf(m_run[r], mt);
      float ssum = 0.f;
#pragma unroll
      for (int c = 0; c < 4; c++) ssum += __expf(val[c][r] - mn);
#pragma unroll
      for (int off = 1; off < 16; off <<= 1) ssum += __shfl_xor(ssum, off, 16);
      l_run[r] = l_run[r] * __expf(m_run[r] - mn) + ssum;
      m_run[r] = mn;
    }
  }

  float rl[4];
#pragma unroll
  for (int r = 0; r < 4; r++) rl[r] = 127.0f / l_run[r];   // l >= 1 always (diagonal)

  v4i accd[8];
#pragma unroll
  for (int c2 = 0; c2 < 8; c2++) accd[c2] = (v4i){0, 0, 0, 0};

  // ---------- pass 2: requantize P and PV ----------
  for (int it = 0; it < ntiles; ++it) {
    int s0 = it * 64;
    __syncthreads();
#pragma unroll
    for (int i2 = 0; i2 < 2; ++i2) {
      int c = tid + i2 * 256;
      int row = c >> 3, koff = (c & 7) * 16;
      int4 v = *(const int4*)(Kc + (size_t)(b * Tdim + s0 + row) * Edim + h * Ddim + koff);
      *(ll_t*)(ks + row * 144 + koff)     = ((const ll_t*)&v)[0];
      *(ll_t*)(ks + row * 144 + koff + 8) = ((const ll_t*)&v)[1];
    }
#pragma unroll
    for (int i2 = 0; i2 < 8; ++i2) {
      int c = tid + i2 * 256;            // 2048 chunks of 4B
      int row = c >> 5, dbase = (c & 31) * 4;
      int vv = *(const int*)(Vc + (size_t)(b * Tdim + s0 + row) * Edim + h * Ddim + dbase);
      char4 cv = *(const char4*)&vv;
      vts[(dbase + 0) * 80 + row] = cv.x;
      vts[(dbase + 1) * 80 + row] = cv.y;
      vts[(dbase + 2) * 80 + row] = cv.z;
      vts[(dbase + 3) * 80 + row] = cv.w;
    }
    __syncthreads();

#pragma unroll
    for (int c = 0; c < 4; c++) {
      v4i acc = (v4i){0, 0, 0, 0};
#pragma unroll
      for (int kk = 0; kk < 4; kk++) {
        ll_t a  = *(const ll_t*)(qs + (16 * wave + l16) * 144 + kk * 32 + quad * 8);
        ll_t bb = *(const ll_t*)(ks + (16 * c + l16) * 144 + kk * 32 + quad * 8);
        acc = __builtin_amdgcn_mfma_i32_16x16x32_i8(a, bb, acc, 0, 0, 0);
      }
      int s = s0 + 16 * c + l16;
#pragma unroll
      for (int r = 0; r < 4; r++) {
        int t = t0 + 16 * wave + quad * 4 + r;
        float p = 0.f;
        if (s <= t)
          p = rintf(__expf((float)acc[r] * a_qk - m_run[r]) * rl[r]);
        ps[wave][(quad * 4 + r) * 72 + 16 * c + l16] = (char)(int)p;
      }
    }
    __syncthreads();

#pragma unroll
    for (int kk2 = 0; kk2 < 2; ++kk2) {
      ll_t a = *(const ll_t*)(ps[wave] + l16 * 72 + kk2 * 32 + quad * 8);
#pragma unroll
      for (int c2 = 0; c2 < 8; ++c2) {
        ll_t bb = *(const ll_t*)(vts + (16 * c2 + l16) * 80 + kk2 * 32 + quad * 8);
        accd[c2] = __builtin_amdgcn_mfma_i32_16x16x32_i8(a, bb, accd[c2], 0, 0, 0);
      }
    }
  }

  // write ctx int8
#pragma unroll
  for (int c2 = 0; c2 < 8; ++c2) {
    int d = 16 * c2 + l16;
#pragma unroll
    for (int r = 0; r < 4; r++) {
      int t = t0 + 16 * wave + quad * 4 + r;
      float y = a_pv * (float)accd[c2][r];
      int q = (int)rintf(y);
      q = q < -128 ? -128 : (q > 127 ? 127 : q);
      CTX[(size_t)(b * Tdim + t) * Edim + h * Ddim + d] = (char)q;
    }
  }
}

// ---------------- launch ----------------
extern "C" void kernel_launch(void* const* d_in, const int* in_sizes, int n_in,
                              void* d_out, int out_size, void* d_ws, size_t ws_size,
                              hipStream_t stream) {
  const int*   hs  = (const int*)d_in[0];
  const int*   Wq  = (const int*)d_in[1];
  const int*   bq  = (const int*)d_in[2];
  const int*   Wk  = (const int*)d_in[3];
  const int*   bk  = (const int*)d_in[4];
  const int*   Wv  = (const int*)d_in[5];
  const int*   bv  = (const int*)d_in[6];
  const int*   Wo  = (const int*)d_in[7];
  const float* bo  = (const float*)d_in[8];
  // d_in[9] = attention_mask: deterministic causal, computed analytically (not read)
  const float* aq  = (const float*)d_in[10];
  const float* ak  = (const float*)d_in[11];
  const float* av  = (const float*)d_in[12];
  const float* aqk = (const float*)d_in[13];
  const float* apv = (const float*)d_in[14];
  const float* ao  = (const float*)d_in[15];

  char* ws = (char*)d_ws;
  const size_t SZ = (size_t)Mdim * Edim;   // 16 MiB per int8 buffer
  char* h8   = ws + 0 * SZ;
  char* wq8  = ws + 1 * SZ;
  char* wk8  = ws + 2 * SZ;
  char* wv8  = ws + 3 * SZ;
  char* wo8  = ws + 4 * SZ;
  char* q8   = ws + 5 * SZ;
  char* k8   = ws + 6 * SZ;
  char* v8   = ws + 7 * SZ;
  char* ctx8 = h8;                         // reuse: hidden no longer needed post-QKV

  const int n4 = (int)(SZ / 4);
  pack_i8_kernel<<<4096, 256, 0, stream>>>(hs, h8, n4);
  pack_i8_kernel<<<4096, 256, 0, stream>>>(Wq, wq8, n4);
  pack_i8_kernel<<<4096, 256, 0, stream>>>(Wk, wk8, n4);
  pack_i8_kernel<<<4096, 256, 0, stream>>>(Wv, wv8, n4);
  pack_i8_kernel<<<4096, 256, 0, stream>>>(Wo, wo8, n4);

  dim3 gg(32, 32);
  gemm_nt_i8<0><<<gg, 256, 0, stream>>>(h8, wq8, bq, (const float*)nullptr, aq, q8, (float*)nullptr);
  gemm_nt_i8<0><<<gg, 256, 0, stream>>>(h8, wk8, bk, (const float*)nullptr, ak, k8, (float*)nullptr);
  gemm_nt_i8<0><<<gg, 256, 0, stream>>>(h8, wv8, bv, (const float*)nullptr, av, v8, (float*)nullptr);

  attn_kernel<<<dim3(32, 64), 256, 0, stream>>>(q8, k8, v8, aqk, apv, ctx8);

  gemm_nt_i8<1><<<gg, 256, 0, stream>>>(ctx8, wo8, (const int*)nullptr, bo, ao,
                                        (char*)nullptr, (float*)d_out);
}

// Round 4
// 952.064 us; speedup vs baseline: 1.7213x; 1.7213x over previous
//
#include <hip/hip_runtime.h>

#define Bdim 2
#define Tdim 2048
#define Edim 4096
#define Hdim 32
#define Ddim 128
#define Mdim (Bdim*Tdim)   // 4096
#define Kdim 4096

typedef int v4i __attribute__((ext_vector_type(4)));

// glds16: HW semantics = wave-uniform base (readfirstlane) + lane*16; we pass
// base + cidx*16 with cidx consecutive in lane order (correct either way).
__device__ __forceinline__ void glds16(const void* g, void* l) {
  __builtin_amdgcn_global_load_lds(
      (const __attribute__((address_space(1))) void*)g,
      (__attribute__((address_space(3))) void*)l, 16, 0, 0);
}

// ---------------- fused pack: 5x int32 -> int8 ----------------
// grid: (SZ/4/256 = 16384, 5); one int4 chunk per thread. (Round-2 bug: 4096
// blocks covered only 1/4 of each buffer, leaving 0xAA poison -> absmax 36928.)
__global__ __launch_bounds__(256) void pack5_kernel(
    const int* __restrict__ s0, const int* __restrict__ s1, const int* __restrict__ s2,
    const int* __restrict__ s3, const int* __restrict__ s4,
    char* __restrict__ d0, char* __restrict__ d1, char* __restrict__ d2,
    char* __restrict__ d3, char* __restrict__ d4) {
  int which = blockIdx.y;
  const int* s = which == 0 ? s0 : which == 1 ? s1 : which == 2 ? s2 : which == 3 ? s3 : s4;
  char* d = which == 0 ? d0 : which == 1 ? d1 : which == 2 ? d2 : which == 3 ? d3 : d4;
  int i = blockIdx.x * 256 + threadIdx.x;
  int4 x = ((const int4*)s)[i];
  char4 y; y.x = (char)x.x; y.y = (char)x.y; y.z = (char)x.z; y.w = (char)x.w;
  ((char4*)d)[i] = y;
}

// ---------------- V transpose: v8[b][s][h*128+d] -> vt[bh][d][s] ----------------
__global__ __launch_bounds__(256) void transpose_v(const char* __restrict__ V8,
                                                   char* __restrict__ Vt) {
  int bh = blockIdx.z, b = bh >> 5, h = bh & 31;
  int s0 = blockIdx.x * 64, d0 = blockIdx.y * 64;
  __shared__ __align__(16) char tl[64 * 80];
  int idx = threadIdx.x;
  {
    int row = idx >> 2, off = (idx & 3) * 16;
    v4i v = *(const v4i*)(V8 + (size_t)(b * Tdim + s0 + row) * Edim + h * Ddim + d0 + off);
    *(v4i*)(tl + row * 80 + off) = v;
  }
  __syncthreads();
  {
    int drow = idx >> 2, soff = (idx & 3) * 16;
    char out[16];
#pragma unroll
    for (int j = 0; j < 16; j++) out[j] = tl[(soff + j) * 80 + drow];
    *(v4i*)(Vt + ((size_t)bh * Ddim + d0 + drow) * Tdim + s0 + soff) = *(v4i*)out;
  }
}

// ---------------- int8 NT GEMM: C[m][n] = sum_k A[m][k]*B[n][k] ----------------
template<int OUT_MODE>
__global__ __launch_bounds__(256) void gemm_nt_i8(
    const char* __restrict__ A, const char* __restrict__ Bw,
    const int* __restrict__ bias_i, const float* __restrict__ bias_f,
    const float* __restrict__ alpha_p,
    char* __restrict__ out8, float* __restrict__ outf)
{
  const float alpha = alpha_p[0];
  const int tid = threadIdx.x;
  const int wave = tid >> 6, lane = tid & 63;
  const int quad = lane >> 4, l16 = lane & 15;
  const int wr = wave & 1, wc = wave >> 1;
  const int m0 = blockIdx.x * 128, n0 = blockIdx.y * 128;

  __shared__ __align__(16) char As[128 * 64];
  __shared__ __align__(16) char Bs[128 * 64];

  // staging addresses (chunk idx = (wave*2+j)*64 + lane; LDS addr = 16*cidx)
  const char* ga[2]; const char* gb[2]; char* la[2]; char* lb[2];
#pragma unroll
  for (int j = 0; j < 2; j++) {
    int cidx = (wave * 2 + j) * 64 + lane;
    int row = cidx >> 2, koff = (cidx & 3) * 16;
    ga[j] = A  + (size_t)(m0 + row) * Kdim + koff;
    gb[j] = Bw + (size_t)(n0 + row) * Kdim + koff;
    la[j] = As + cidx * 16;     // per-lane LDS target (lane-contiguous)
    lb[j] = Bs + cidx * 16;
  }

  v4i acc[4][4];
#pragma unroll
  for (int i = 0; i < 4; i++)
#pragma unroll
    for (int c = 0; c < 4; c++) acc[i][c] = (v4i){0, 0, 0, 0};

  for (int k0 = 0; k0 < Kdim; k0 += 64) {
    __syncthreads();
    glds16(ga[0] + k0, la[0]);
    glds16(ga[1] + k0, la[1]);
    glds16(gb[0] + k0, lb[0]);
    glds16(gb[1] + k0, lb[1]);
    __syncthreads();

    v4i af[4], bf[4];
#pragma unroll
    for (int i = 0; i < 4; i++)
      af[i] = *(const v4i*)(As + (64 * wr + 16 * i + l16) * 64 + quad * 16);
#pragma unroll
    for (int c = 0; c < 4; c++)
      bf[c] = *(const v4i*)(Bs + (64 * wc + 16 * c + l16) * 64 + quad * 16);
#pragma unroll
    for (int i = 0; i < 4; i++)
#pragma unroll
      for (int c = 0; c < 4; c++)
        acc[i][c] = __builtin_amdgcn_mfma_i32_16x16x64_i8(af[i], bf[c], acc[i][c], 0, 0, 0);
  }

#pragma unroll
  for (int i = 0; i < 4; i++) {
#pragma unroll
    for (int c = 0; c < 4; c++) {
      int gcol = n0 + 64 * wc + 16 * c + l16;
#pragma unroll
      for (int r = 0; r < 4; r++) {
        int grow = m0 + 64 * wr + 16 * i + quad * 4 + r;
        float y = (float)acc[i][c][r] * alpha;
        if (OUT_MODE == 0) {
          y += (float)bias_i[gcol];
          int q = (int)rintf(y);
          q = q < -128 ? -128 : (q > 127 ? 127 : q);
          out8[(size_t)grow * 4096 + gcol] = (char)q;
        } else {
          outf[(size_t)grow * 4096 + gcol] = y + bias_f[gcol];
        }
      }
    }
  }
}

// ---------------- fused int8 attention (S^T formulation) ----------------
// grid: (T/64, B*H); block 256 = 4 waves; wave w owns t rows [t0+16w, t0+16w+16)
__global__ __launch_bounds__(256) void attn_kernel(
    const char* __restrict__ Q, const char* __restrict__ Kc, const char* __restrict__ Vt,
    const float* __restrict__ aqk_p, const float* __restrict__ apv_p,
    char* __restrict__ CTX)
{
  const int tid = threadIdx.x;
  const int wave = tid >> 6, lane = tid & 63;
  const int quad = lane >> 4, l16 = lane & 15;
  const int bh = blockIdx.y, b = bh >> 5, h = bh & 31;
  const int t0 = (gridDim.x - 1 - blockIdx.x) * 64;   // heavy blocks first
  const int ntiles = (t0 >> 6) + 1;
  const float a_qk = aqk_p[0], a_pv = apv_p[0];

  __shared__ __align__(16) char qs[64 * 128];   // xor-swizzled rows
  __shared__ __align__(16) char ks[64 * 128];   // xor-swizzled rows
  __shared__ __align__(16) char vts[128 * 64];  // natural [d][s] tile
  __shared__ __align__(16) char ps[4][16 * 80]; // per-wave P^T [t][s], stride 80

  const int t = t0 + 16 * wave + l16;
  const int h7 = l16 & 7;

  // stage Q tile (swizzled)
#pragma unroll
  for (int j = 0; j < 2; j++) {
    int idx = tid + j * 256;
    int row = idx >> 3, ch = idx & 7;
    v4i v = *(const v4i*)(Q + (size_t)(b * Tdim + t0 + row) * Edim + h * Ddim + ch * 16);
    *(v4i*)(qs + row * 128 + ((ch ^ (row & 7)) * 16)) = v;
  }
  __syncthreads();
  v4i qB[2];
#pragma unroll
  for (int kk = 0; kk < 2; kk++)
    qB[kk] = *(const v4i*)(qs + (wave * 16 + l16) * 128 + (((4 * kk + quad) ^ h7) * 16));

  float m_run = -1e30f, l_run = 0.f;

  // ---------- pass 1: exact row max & denom ----------
  for (int it = 0; it < ntiles; ++it) {
    int s0 = it * 64;
    __syncthreads();
#pragma unroll
    for (int j = 0; j < 2; j++) {
      int idx = tid + j * 256;
      int row = idx >> 3, ch = idx & 7;
      v4i v = *(const v4i*)(Kc + (size_t)(b * Tdim + s0 + row) * Edim + h * Ddim + ch * 16);
      *(v4i*)(ks + row * 128 + ((ch ^ (row & 7)) * 16)) = v;
    }
    __syncthreads();

    float sv[4][4];
#pragma unroll
    for (int c = 0; c < 4; c++) {
      v4i acc = (v4i){0, 0, 0, 0};
#pragma unroll
      for (int kk = 0; kk < 2; kk++) {
        v4i aK = *(const v4i*)(ks + (16 * c + l16) * 128 + (((4 * kk + quad) ^ h7) * 16));
        acc = __builtin_amdgcn_mfma_i32_16x16x64_i8(aK, qB[kk], acc, 0, 0, 0);
      }
#pragma unroll
      for (int r = 0; r < 4; r++) {
        int s = s0 + 16 * c + 4 * quad + r;
        sv[c][r] = (s <= t) ? (float)acc[r] * a_qk : -1e30f;
      }
    }
    float mt = -1e30f;
#pragma unroll
    for (int c = 0; c < 4; c++)
#pragma unroll
      for (int r = 0; r < 4; r++) mt = fmaxf(mt, sv[c][r]);
    mt = fmaxf(mt, __shfl_xor(mt, 16));
    mt = fmaxf(mt, __shfl_xor(mt, 32));
    float mn = fmaxf(m_run, mt);
    float ss = 0.f;
#pragma unroll
    for (int c = 0; c < 4; c++)
#pragma unroll
      for (int r = 0; r < 4; r++) ss += __expf(sv[c][r] - mn);
    ss += __shfl_xor(ss, 16);
    ss += __shfl_xor(ss, 32);
    l_run = l_run * __expf(m_run - mn) + ss;
    m_run = mn;
  }

  const float rl = 127.0f / l_run;

  v4i accd[8];
#pragma unroll
  for (int dt = 0; dt < 8; dt++) accd[dt] = (v4i){0, 0, 0, 0};

  // ---------- pass 2: requantize P^T, PV via out^T = V^T . P ----------
  for (int it = 0; it < ntiles; ++it) {
    int s0 = it * 64;
    __syncthreads();
#pragma unroll
    for (int j = 0; j < 2; j++) {
      int idx = tid + j * 256;
      int row = idx >> 3, ch = idx & 7;
      v4i v = *(const v4i*)(Kc + (size_t)(b * Tdim + s0 + row) * Edim + h * Ddim + ch * 16);
      *(v4i*)(ks + row * 128 + ((ch ^ (row & 7)) * 16)) = v;
    }
#pragma unroll
    for (int j = 0; j < 2; j++) {
      int cidx = (wave * 2 + j) * 64 + lane;
      int row = cidx >> 2, off = (cidx & 3) * 16;
      glds16(Vt + ((size_t)bh * Ddim + row) * Tdim + s0 + off, vts + cidx * 16);
    }
    __syncthreads();

#pragma unroll
    for (int c = 0; c < 4; c++) {
      v4i acc = (v4i){0, 0, 0, 0};
#pragma unroll
      for (int kk = 0; kk < 2; kk++) {
        v4i aK = *(const v4i*)(ks + (16 * c + l16) * 128 + (((4 * kk + quad) ^ h7) * 16));
        acc = __builtin_amdgcn_mfma_i32_16x16x64_i8(aK, qB[kk], acc, 0, 0, 0);
      }
      char4 pc;
#pragma unroll
      for (int r = 0; r < 4; r++) {
        int s = s0 + 16 * c + 4 * quad + r;
        float p = 0.f;
        if (s <= t)
          p = rintf(__expf((float)acc[r] * a_qk - m_run) * rl);
        ((char*)&pc)[r] = (char)(int)p;
      }
      *(char4*)(ps[wave] + l16 * 80 + 16 * c + 4 * quad) = pc;
    }
    // per-wave buffer: enforce DS write->read ordering before B-frag read
    asm volatile("s_waitcnt lgkmcnt(0)" ::: "memory");
    v4i bP = *(const v4i*)(ps[wave] + l16 * 80 + quad * 16);
#pragma unroll
    for (int dt = 0; dt < 8; dt++) {
      v4i aV = *(const v4i*)(vts + (16 * dt + l16) * 64 + quad * 16);
      accd[dt] = __builtin_amdgcn_mfma_i32_16x16x64_i8(aV, bP, accd[dt], 0, 0, 0);
    }
  }

  // write ctx int8: lane holds d = 16dt + 4quad + r for its t
  size_t obase = (size_t)(b * Tdim + t) * Edim + h * Ddim;
#pragma unroll
  for (int dt = 0; dt < 8; dt++) {
    char4 oc;
#pragma unroll
    for (int r = 0; r < 4; r++) {
      int q = (int)rintf(a_pv * (float)accd[dt][r]);
      q = q < -128 ? -128 : (q > 127 ? 127 : q);
      ((char*)&oc)[r] = (char)q;
    }
    *(char4*)(CTX + obase + 16 * dt + 4 * quad) = oc;
  }
}

// ---------------- launch ----------------
extern "C" void kernel_launch(void* const* d_in, const int* in_sizes, int n_in,
                              void* d_out, int out_size, void* d_ws, size_t ws_size,
                              hipStream_t stream) {
  const int*   hs  = (const int*)d_in[0];
  const int*   Wq  = (const int*)d_in[1];
  const int*   bq  = (const int*)d_in[2];
  const int*   Wk  = (const int*)d_in[3];
  const int*   bk  = (const int*)d_in[4];
  const int*   Wv  = (const int*)d_in[5];
  const int*   bv  = (const int*)d_in[6];
  const int*   Wo  = (const int*)d_in[7];
  const float* bo  = (const float*)d_in[8];
  // d_in[9] = attention_mask: analytic causal, not read
  const float* aq  = (const float*)d_in[10];
  const float* ak  = (const float*)d_in[11];
  const float* av  = (const float*)d_in[12];
  const float* aqk = (const float*)d_in[13];
  const float* apv = (const float*)d_in[14];
  const float* ao  = (const float*)d_in[15];

  char* ws = (char*)d_ws;
  const size_t SZ = (size_t)Mdim * Edim;   // 16 MiB
  char* h8   = ws + 0 * SZ;
  char* wq8  = ws + 1 * SZ;
  char* wk8  = ws + 2 * SZ;
  char* wv8  = ws + 3 * SZ;
  char* wo8  = ws + 4 * SZ;
  char* q8   = ws + 5 * SZ;
  char* k8   = ws + 6 * SZ;
  char* v8   = ws + 7 * SZ;
  char* vt8  = wq8;                        // reuse after QKV GEMMs
  char* ctx8 = h8;                         // reuse after QKV GEMMs

  // SZ/4 chunks of 4 int8 per buffer -> SZ/4/256 = 16384 blocks
  pack5_kernel<<<dim3(16384, 5), 256, 0, stream>>>(hs, Wq, Wk, Wv, Wo,
                                                   h8, wq8, wk8, wv8, wo8);

  dim3 gg(32, 32);
  gemm_nt_i8<0><<<gg, 256, 0, stream>>>(h8, wq8, bq, nullptr, aq, q8, nullptr);
  gemm_nt_i8<0><<<gg, 256, 0, stream>>>(h8, wk8, bk, nullptr, ak, k8, nullptr);
  gemm_nt_i8<0><<<gg, 256, 0, stream>>>(h8, wv8, bv, nullptr, av, v8, nullptr);

  transpose_v<<<dim3(32, 2, 64), 256, 0, stream>>>(v8, vt8);

  attn_kernel<<<dim3(32, 64), 256, 0, stream>>>(q8, k8, vt8, aqk, apv, ctx8);

  gemm_nt_i8<1><<<gg, 256, 0, stream>>>(ctx8, wo8, nullptr, bo, ao, nullptr, (float*)d_out);
}